// Round 5
// baseline (74.744 us; speedup 1.0000x reference)
//
#include <hip/hip_runtime.h>

namespace {

constexpr int H = 128, W = 128;
constexpr int NPIX = H * W;          // 16384 pixels, each float4 over T=4
constexpr float GAMMA_W = 3.3257199f;
constexpr int NSL = 10;              // slices: 5 di x 2 dj-halves

__device__ __forceinline__ void load4(const float4* __restrict__ p, float o[4]) {
    const float4 v = *p;
    o[0] = v.x; o[1] = v.y; o[2] = v.z; o[3] = v.w;
}

// block = 64 pixels x 10 slices (5 di x 2 dj-halves) = 640 threads (10 waves).
// s = tid>>6 is wave-uniform: each wave = 64 pixels, one di, one dj-half.
// Body is a plain unrolled dj loop (NO lambdas -- round-3's lambda caused
// scratch spill, WRITE_SIZE 150 MB).
__global__ __launch_bounds__(640) void statden(
    const float4* __restrict__ noisy,   // [3][NPIX]
    const float4* __restrict__ guid,    // [9][NPIX]
    const float4* __restrict__ est,     // [3][NPIX]
    const float4* __restrict__ var,     // [3][NPIX]
    float4* __restrict__ out)           // [3][NPIX]
{
    const float sig[9] = {0.1f, 0.1f, 0.1f, 50.f, 50.f, 50.f, 10.f, 10.f, 10.f};
    // t(w) <= gamma  <=>  w <= 1 - 1/(2*(gamma^2+1))
    const float WMAX = (float)(1.0 - 1.0 / (2.0 * ((double)GAMMA_W * (double)GAMMA_W + 1.0)));

    const int tid = threadIdx.x;
    const int p   = tid & 63;           // pixel lane
    const int s   = tid >> 6;           // slice 0..9 (wave-uniform)
    const int pid = blockIdx.x * 64 + p;
    const int h   = pid >> 7;
    const int w   = pid & 127;
    const bool halfA = (s < 5);
    const int di    = (halfA ? s : s - 5) - 2;

    // ---- center (hoisted): sig*gc, qc = sum sig*gc^2, est/var centers ----
    float sgc[9][4], qc[4] = {0.f, 0.f, 0.f, 0.f};
    float ecv[3][4], vcv[3][4];
    {
        float g[4];
#pragma unroll
        for (int c = 0; c < 9; ++c) {
            load4(guid + c * NPIX + pid, g);
#pragma unroll
            for (int t = 0; t < 4; ++t) {
                sgc[c][t] = sig[c] * g[t];
                qc[t] += sgc[c][t] * g[t];
            }
        }
#pragma unroll
        for (int c = 0; c < 3; ++c) {
            load4(est + c * NPIX + pid, ecv[c]);
            load4(var + c * NPIX + pid, vcv[c]);
        }
    }

    float acc[3][4] = {};
    float den[4] = {0.f, 0.f, 0.f, 0.f};

    const int hh = h + di;
    const bool rowok = (unsigned)hh < (unsigned)H;   // wave-uniform

#pragma unroll
    for (int dj = -2; dj <= 2; ++dj) {
        // wave-uniform ownership: halfA owns dj<=0 (3 cols), halfB owns dj>=1 (2 cols)
        const bool mine = halfA ? (dj <= 0) : (dj >= 1);
        if (!mine || !rowok) continue;
        const int ww = w + dj;
        if ((unsigned)ww >= (unsigned)W) continue;
        const int q = hh * W + ww;

        float gj[9][4], ej[3][4], vj[3][4], nj[3][4];
#pragma unroll
        for (int c = 0; c < 9; ++c) load4(guid + c * NPIX + q, gj[c]);
#pragma unroll
        for (int c = 0; c < 3; ++c) {
            load4(est   + c * NPIX + q, ej[c]);
            load4(var   + c * NPIX + q, vj[c]);
            load4(noisy + c * NPIX + q, nj[c]);
        }

#pragma unroll
        for (int tt = 0; tt < 4; ++tt) {
            float qj = 0.f;
#pragma unroll
            for (int c = 0; c < 9; ++c) qj += sig[c] * gj[c][tt] * gj[c][tt];
            float cross[4] = {0.f, 0.f, 0.f, 0.f};
#pragma unroll
            for (int c = 0; c < 9; ++c) {
                const float gv = gj[c][tt];
#pragma unroll
                for (int t = 0; t < 4; ++t) cross[t] += gv * sgc[c][t];
            }
#pragma unroll
            for (int t = 0; t < 4; ++t) {
                if (tt - t > 2 || t - tt > 2) continue;   // |dk|>2: not a patch
                const float sv = qj + qc[t] - 2.f * cross[t];
                bool member = true;
#pragma unroll
                for (int c = 0; c < 3; ++c) {
                    const float ejv = ej[c][tt], vjv = vj[c][tt];
                    const float d   = ecv[c][t] - ejv;
                    const float d2  = d * d;
                    const float S   = vcv[c][t] + vjv;
                    const float num = 2.f * d2 + S;
                    const float dn  = num + S;          // = 2*(d2 + vi + vj)
                    bool pass = (num <= WMAX * dn);     // den==0 -> 0<=0 pass (w=0.5)
                    if (((vcv[c][t] == 0.f) || (vjv == 0.f)) && (d != 0.f)) pass = false;
                    member = member && pass;
                }
                const float f = member ? __expf(-0.5f * sv) : 0.f;
                den[t] += f;
#pragma unroll
                for (int c = 0; c < 3; ++c) acc[c][t] += f * nj[c][tt];
            }
        }
    }

    // ---- reduce the 10 slices via LDS (inner dim 17: coprime with 32 banks) ----
    __shared__ float red[NSL][64][17];
    {
        float* r = &red[s][p][0];
#pragma unroll
        for (int c = 0; c < 3; ++c)
#pragma unroll
            for (int t = 0; t < 4; ++t) r[c * 4 + t] = acc[c][t];
#pragma unroll
        for (int t = 0; t < 4; ++t) r[12 + t] = den[t];
    }
    __syncthreads();

    // 10 -> 5
    if (tid < 5 * 64) {
        float* a = &red[s][p][0];
        const float* b = &red[s + 5][p][0];
#pragma unroll
        for (int i = 0; i < 16; ++i) a[i] += b[i];
    }
    __syncthreads();

    if (tid < 64) {
        // s == 0 here, so this thread's ecv/qc are its own pixel's centers.
#pragma unroll
        for (int c = 0; c < 3; ++c)
#pragma unroll
            for (int t = 0; t < 4; ++t) acc[c][t] = red[0][p][c * 4 + t];
#pragma unroll
        for (int t = 0; t < 4; ++t) den[t] = red[0][p][12 + t];
#pragma unroll
        for (int k = 1; k < 5; ++k) {
            const float* r2 = &red[k][p][0];
#pragma unroll
            for (int c = 0; c < 3; ++c)
#pragma unroll
                for (int t = 0; t < 4; ++t) acc[c][t] += r2[c * 4 + t];
#pragma unroll
            for (int t = 0; t < 4; ++t) den[t] += r2[12 + t];
        }

        // ---- OOB (zero-padded) patches: member iff all ec==0; bw = exp(-qc/2) ----
        const int nh  = min(h + 2, H - 1) - max(h - 2, 0) + 1;
        const int nw  = min(w + 2, W - 1) - max(w - 2, 0) + 1;
        const int nhw = nh * nw;
        const int ntt[4] = {3, 4, 4, 3};
#pragma unroll
        for (int t = 0; t < 4; ++t) {
            const int oob = 125 - nhw * ntt[t];
            const bool allz = (ecv[0][t] == 0.f) && (ecv[1][t] == 0.f) && (ecv[2][t] == 0.f);
            const float f = allz ? __expf(-0.5f * qc[t]) : 0.f;
            den[t] += (float)oob * f;
        }

#pragma unroll
        for (int t = 0; t < 4; ++t) {
            const float inv = 1.0f / fmaxf(den[t], 1e-12f);
#pragma unroll
            for (int c = 0; c < 3; ++c) acc[c][t] *= inv;
        }
#pragma unroll
        for (int c = 0; c < 3; ++c) {
            float4 v;
            v.x = acc[c][0]; v.y = acc[c][1]; v.z = acc[c][2]; v.w = acc[c][3];
            out[c * NPIX + pid] = v;
        }
    }
}

} // namespace

extern "C" void kernel_launch(void* const* d_in, const int* in_sizes, int n_in,
                              void* d_out, int out_size, void* d_ws, size_t ws_size,
                              hipStream_t stream)
{
    const float4* noisy = (const float4*)d_in[0];
    const float4* guid  = (const float4*)d_in[1];
    const float4* est   = (const float4*)d_in[2];
    const float4* var   = (const float4*)d_in[3];
    float4* out = (float4*)d_out;

    statden<<<NPIX / 64, 640, 0, stream>>>(noisy, guid, est, var, out);
}

// Round 6
// 65.256 us; speedup vs baseline: 1.1454x; 1.1454x over previous
//
#include <hip/hip_runtime.h>

namespace {

constexpr int H = 128, W = 128;
constexpr int NPIX = H * W;          // 16384 pixels, each float4 over T=4
constexpr float GAMMA_W = 3.3257199f;
constexpr int NSL = 10;              // slices: 5 di x 2 dj-halves

__device__ __forceinline__ void load4(const float4* __restrict__ p, float o[4]) {
    const float4 v = *p;
    o[0] = v.x; o[1] = v.y; o[2] = v.z; o[3] = v.w;
}

// block = 64 pixels x 10 slices (5 di x 2 dj-halves) = 640 threads (10 waves).
// s = tid>>6 is wave-uniform: each wave = 64 pixels, one di, one dj-half.
//
// __launch_bounds__(640, 2): the min-waves/EU=2 arg is ESSENTIAL. Without it
// the backend derives an occupancy target from the 43.5 KB LDS (3 blocks/CU
// -> 7.5 waves/EU) and throttles registers to ~84 VGPR -> ~900 B/thread
// scratch spill (rounds 3 & 5: FETCH/WRITE ~140 MB, dur 75-80 us).
__global__ __launch_bounds__(640, 2) void statden(
    const float4* __restrict__ noisy,   // [3][NPIX]
    const float4* __restrict__ guid,    // [9][NPIX]
    const float4* __restrict__ est,     // [3][NPIX]
    const float4* __restrict__ var,     // [3][NPIX]
    float4* __restrict__ out)           // [3][NPIX]
{
    const float sig[9] = {0.1f, 0.1f, 0.1f, 50.f, 50.f, 50.f, 10.f, 10.f, 10.f};
    // t(w) <= gamma  <=>  w <= 1 - 1/(2*(gamma^2+1))
    const float WMAX = (float)(1.0 - 1.0 / (2.0 * ((double)GAMMA_W * (double)GAMMA_W + 1.0)));

    const int tid = threadIdx.x;
    const int p   = tid & 63;           // pixel lane
    const int s   = tid >> 6;           // slice 0..9 (wave-uniform)
    const int pid = blockIdx.x * 64 + p;
    const int h   = pid >> 7;
    const int w   = pid & 127;
    const bool halfA = (s < 5);
    const int di    = (halfA ? s : s - 5) - 2;

    // ---- center (hoisted): sig*gc, qc = sum sig*gc^2, est/var centers ----
    float sgc[9][4], qc[4] = {0.f, 0.f, 0.f, 0.f};
    float ecv[3][4], vcv[3][4];
    {
        float g[4];
#pragma unroll
        for (int c = 0; c < 9; ++c) {
            load4(guid + c * NPIX + pid, g);
#pragma unroll
            for (int t = 0; t < 4; ++t) {
                sgc[c][t] = sig[c] * g[t];
                qc[t] += sgc[c][t] * g[t];
            }
        }
#pragma unroll
        for (int c = 0; c < 3; ++c) {
            load4(est + c * NPIX + pid, ecv[c]);
            load4(var + c * NPIX + pid, vcv[c]);
        }
    }

    float acc[3][4] = {};
    float den[4] = {0.f, 0.f, 0.f, 0.f};

    const int hh = h + di;
    if ((unsigned)hh < (unsigned)H) {   // wave-uniform row guard
#pragma unroll
        for (int dj = -2; dj <= 2; ++dj) {
            // wave-uniform ownership: halfA owns dj<=0 (3 cols), halfB dj>=1 (2 cols)
            const bool mine = halfA ? (dj <= 0) : (dj >= 1);
            if (!mine) continue;
            const int ww = w + dj;
            if ((unsigned)ww >= (unsigned)W) continue;
            const int q = hh * W + ww;

            float gj[9][4], ej[3][4], vj[3][4], nj[3][4];
#pragma unroll
            for (int c = 0; c < 9; ++c) load4(guid + c * NPIX + q, gj[c]);
#pragma unroll
            for (int c = 0; c < 3; ++c) {
                load4(est   + c * NPIX + q, ej[c]);
                load4(var   + c * NPIX + q, vj[c]);
                load4(noisy + c * NPIX + q, nj[c]);
            }

#pragma unroll
            for (int tt = 0; tt < 4; ++tt) {
                float qj = 0.f;
#pragma unroll
                for (int c = 0; c < 9; ++c) qj += sig[c] * gj[c][tt] * gj[c][tt];
                float cross[4] = {0.f, 0.f, 0.f, 0.f};
#pragma unroll
                for (int c = 0; c < 9; ++c) {
                    const float gv = gj[c][tt];
#pragma unroll
                    for (int t = 0; t < 4; ++t) cross[t] += gv * sgc[c][t];
                }
#pragma unroll
                for (int t = 0; t < 4; ++t) {
                    if (tt - t > 2 || t - tt > 2) continue;   // |dk|>2: not a patch
                    const float sv = qj + qc[t] - 2.f * cross[t];
                    bool member = true;
#pragma unroll
                    for (int c = 0; c < 3; ++c) {
                        const float ejv = ej[c][tt], vjv = vj[c][tt];
                        const float d   = ecv[c][t] - ejv;
                        const float d2  = d * d;
                        const float S   = vcv[c][t] + vjv;
                        const float num = 2.f * d2 + S;
                        const float dn  = num + S;          // = 2*(d2 + vi + vj)
                        bool pass = (num <= WMAX * dn);     // den==0 -> 0<=0 pass (w=0.5)
                        if (((vcv[c][t] == 0.f) || (vjv == 0.f)) && (d != 0.f)) pass = false;
                        member = member && pass;
                    }
                    const float f = member ? __expf(-0.5f * sv) : 0.f;
                    den[t] += f;
#pragma unroll
                    for (int c = 0; c < 3; ++c) acc[c][t] += f * nj[c][tt];
                }
            }
        }
    }

    // ---- reduce the 10 slices via LDS (inner dim 17: coprime with 32 banks) ----
    __shared__ float red[NSL][64][17];
    {
        float* r = &red[s][p][0];
#pragma unroll
        for (int c = 0; c < 3; ++c)
#pragma unroll
            for (int t = 0; t < 4; ++t) r[c * 4 + t] = acc[c][t];
#pragma unroll
        for (int t = 0; t < 4; ++t) r[12 + t] = den[t];
    }
    __syncthreads();

    // 10 -> 5
    if (tid < 5 * 64) {
        float* a = &red[s][p][0];
        const float* b = &red[s + 5][p][0];
#pragma unroll
        for (int i = 0; i < 16; ++i) a[i] += b[i];
    }
    __syncthreads();

    if (tid < 64) {
        // s == 0 here, so this thread's ecv/qc are its own pixel's centers.
#pragma unroll
        for (int c = 0; c < 3; ++c)
#pragma unroll
            for (int t = 0; t < 4; ++t) acc[c][t] = red[0][p][c * 4 + t];
#pragma unroll
        for (int t = 0; t < 4; ++t) den[t] = red[0][p][12 + t];
#pragma unroll
        for (int k = 1; k < 5; ++k) {
            const float* r2 = &red[k][p][0];
#pragma unroll
            for (int c = 0; c < 3; ++c)
#pragma unroll
                for (int t = 0; t < 4; ++t) acc[c][t] += r2[c * 4 + t];
#pragma unroll
            for (int t = 0; t < 4; ++t) den[t] += r2[12 + t];
        }

        // ---- OOB (zero-padded) patches: member iff all ec==0; bw = exp(-qc/2) ----
        const int nh  = min(h + 2, H - 1) - max(h - 2, 0) + 1;
        const int nw  = min(w + 2, W - 1) - max(w - 2, 0) + 1;
        const int nhw = nh * nw;
        const int ntt[4] = {3, 4, 4, 3};
#pragma unroll
        for (int t = 0; t < 4; ++t) {
            const int oob = 125 - nhw * ntt[t];
            const bool allz = (ecv[0][t] == 0.f) && (ecv[1][t] == 0.f) && (ecv[2][t] == 0.f);
            const float f = allz ? __expf(-0.5f * qc[t]) : 0.f;
            den[t] += (float)oob * f;
        }

#pragma unroll
        for (int t = 0; t < 4; ++t) {
            const float inv = 1.0f / fmaxf(den[t], 1e-12f);
#pragma unroll
            for (int c = 0; c < 3; ++c) acc[c][t] *= inv;
        }
#pragma unroll
        for (int c = 0; c < 3; ++c) {
            float4 v;
            v.x = acc[c][0]; v.y = acc[c][1]; v.z = acc[c][2]; v.w = acc[c][3];
            out[c * NPIX + pid] = v;
        }
    }
}

} // namespace

extern "C" void kernel_launch(void* const* d_in, const int* in_sizes, int n_in,
                              void* d_out, int out_size, void* d_ws, size_t ws_size,
                              hipStream_t stream)
{
    const float4* noisy = (const float4*)d_in[0];
    const float4* guid  = (const float4*)d_in[1];
    const float4* est   = (const float4*)d_in[2];
    const float4* var   = (const float4*)d_in[3];
    float4* out = (float4*)d_out;

    statden<<<NPIX / 64, 640, 0, stream>>>(noisy, guid, est, var, out);
}

// Round 7
// 34.029 us; speedup vs baseline: 2.1965x; 1.9176x over previous
//
#include <hip/hip_runtime.h>

namespace {

constexpr int H = 128, W = 128;
constexpr int NPIX = H * W;           // 16384 pixels, each float4 over T=4
constexpr float GAMMA_W = 3.3257199f;
// t(w) <= gamma  <=>  w <= 1 - 1/(2*(gamma^2+1))
__device__ constexpr float WMAX = (float)(1.0 - 1.0 / (2.0 * ((double)GAMMA_W * (double)GAMMA_W + 1.0)));

__device__ __forceinline__ void load4(const float4* __restrict__ p, float o[4]) {
    const float4 v = *p;
    o[0] = v.x; o[1] = v.y; o[2] = v.z; o[3] = v.w;
}

// ================= K1: per-(dj, pixel-group) partials =================
// blockIdx.x = pg*5 + bh  (dj = bh-2). block = 64 px * 5 waves (wave s: di = s-2).
// Each thread: ONE column (di,dj) for its pixel, all 4 t. Small working set.
// amdgpu_waves_per_eu(2,8): min=2 -> VGPR cap 256; overrides the backend's
// LDS-derived occupancy target that pinned 640-thread builds to 84 VGPR
// (rounds 3/5/6: ~140 MB scratch spill traffic).
__global__ __launch_bounds__(320)
__attribute__((amdgpu_waves_per_eu(2, 8)))
void statden_part(const float4* __restrict__ noisy,
                  const float4* __restrict__ guid,
                  const float4* __restrict__ est,
                  const float4* __restrict__ var,
                  float4* __restrict__ ws)      // [5][NPIX][4] float4s
{
    const float sig[9] = {0.1f, 0.1f, 0.1f, 50.f, 50.f, 50.f, 10.f, 10.f, 10.f};

    const int tid = threadIdx.x;
    const int p   = tid & 63;
    const int s   = tid >> 6;          // wave id: di = s-2 (wave-uniform)
    const int bh  = blockIdx.x % 5;    // dj = bh-2 (block-uniform)
    const int pg  = blockIdx.x / 5;
    const int pid = pg * 64 + p;
    const int h   = pid >> 7;
    const int w   = pid & 127;

    // ---- centers: raw gc (sig folded into the j-side), qc, est/var ----
    float gc[9][4], qc[4] = {0.f, 0.f, 0.f, 0.f};
    float ecv[3][4], vcv[3][4];
#pragma unroll
    for (int c = 0; c < 9; ++c) {
        load4(guid + c * NPIX + pid, gc[c]);
#pragma unroll
        for (int t = 0; t < 4; ++t) qc[t] += sig[c] * gc[c][t] * gc[c][t];
    }
#pragma unroll
    for (int c = 0; c < 3; ++c) {
        load4(est + c * NPIX + pid, ecv[c]);
        load4(var + c * NPIX + pid, vcv[c]);
    }

    float acc[3][4] = {};
    float den[4] = {0.f, 0.f, 0.f, 0.f};

    const int hh = h + s - 2;          // wave-uniform guard
    const int ww = w + bh - 2;         // per-lane guard only at row edges
    if (((unsigned)hh < (unsigned)H) && ((unsigned)ww < (unsigned)W)) {
        const int q = hh * W + ww;

        // phase 1: guidance quadratic, c-wise (gj consumed immediately)
        float qj[4] = {0.f, 0.f, 0.f, 0.f};
        float cross[4][4] = {};
#pragma unroll
        for (int c = 0; c < 9; ++c) {
            float g4[4];
            load4(guid + c * NPIX + q, g4);
            float s4[4];
#pragma unroll
            for (int tt = 0; tt < 4; ++tt) s4[tt] = sig[c] * g4[tt];
#pragma unroll
            for (int tt = 0; tt < 4; ++tt) qj[tt] += s4[tt] * g4[tt];
#pragma unroll
            for (int t = 0; t < 4; ++t)
#pragma unroll
                for (int tt = 0; tt < 4; ++tt) cross[t][tt] += s4[tt] * gc[c][t];
        }

        // phase 2: membership mask per (t,tt); invalid |t-tt|>2 pairs start at 0
        float mf[4][4];
#pragma unroll
        for (int t = 0; t < 4; ++t)
#pragma unroll
            for (int tt = 0; tt < 4; ++tt)
                mf[t][tt] = (tt - t > 2 || t - tt > 2) ? 0.f : 1.f;
#pragma unroll
        for (int c = 0; c < 3; ++c) {
            float ej4[4], vj4[4];
            load4(est + c * NPIX + q, ej4);
            load4(var + c * NPIX + q, vj4);
#pragma unroll
            for (int t = 0; t < 4; ++t)
#pragma unroll
                for (int tt = 0; tt < 4; ++tt) {
                    const float d   = ecv[c][t] - ej4[tt];
                    const float d2  = d * d;
                    const float S   = vcv[c][t] + vj4[tt];
                    const float num = 2.f * d2 + S;
                    const float dn  = num + S;           // = 2*(d2+vi+vj)
                    bool pass = (num <= WMAX * dn);      // den==0 -> 0<=0 pass (w=0.5)
                    if (((vcv[c][t] == 0.f) || (vj4[tt] == 0.f)) && (d != 0.f)) pass = false;
                    mf[t][tt] = pass ? mf[t][tt] : 0.f;
                }
        }

        // phase 3: weights + accumulate
        float f[4][4];
#pragma unroll
        for (int t = 0; t < 4; ++t)
#pragma unroll
            for (int tt = 0; tt < 4; ++tt)
                f[t][tt] = mf[t][tt] * __expf(-0.5f * (qj[tt] + qc[t] - 2.f * cross[t][tt]));
#pragma unroll
        for (int t = 0; t < 4; ++t)
            den[t] = (f[t][0] + f[t][1]) + (f[t][2] + f[t][3]);
#pragma unroll
        for (int c = 0; c < 3; ++c) {
            float nj4[4];
            load4(noisy + c * NPIX + q, nj4);
#pragma unroll
            for (int t = 0; t < 4; ++t) {
                float a = f[t][0] * nj4[0];
                a = fmaf(f[t][1], nj4[1], a);
                a = fmaf(f[t][2], nj4[2], a);
                a = fmaf(f[t][3], nj4[3], a);
                acc[c][t] += a;
            }
        }
    }

    // ---- reduce the 5 di-waves via LDS (stride 17: coprime with 32 banks) ----
    __shared__ float red[5][64][17];
    {
        float* r = &red[s][p][0];
#pragma unroll
        for (int c = 0; c < 3; ++c)
#pragma unroll
            for (int t = 0; t < 4; ++t) r[c * 4 + t] = acc[c][t];
#pragma unroll
        for (int t = 0; t < 4; ++t) r[12 + t] = den[t];
    }
    __syncthreads();

    if (tid < 64) {
        float v[16];
#pragma unroll
        for (int i = 0; i < 16; ++i) v[i] = red[0][p][i];
#pragma unroll
        for (int k = 1; k < 5; ++k) {
            const float* r2 = &red[k][p][0];
#pragma unroll
            for (int i = 0; i < 16; ++i) v[i] += r2[i];
        }
        // partial layout: ws[bh][pid] = {acc0, acc1, acc2, den} as 4 float4
        const int base = (bh * NPIX + pid) * 4;
#pragma unroll
        for (int k = 0; k < 4; ++k) {
            float4 o;
            o.x = v[k * 4 + 0]; o.y = v[k * 4 + 1];
            o.z = v[k * 4 + 2]; o.w = v[k * 4 + 3];
            ws[base + k] = o;
        }
    }
}

// ================= K2: combine partials, OOB closed form, divide =================
__global__ __launch_bounds__(256) void statden_final(
    const float4* __restrict__ guid,
    const float4* __restrict__ est,
    const float4* __restrict__ ws,
    float4* __restrict__ out)
{
    const float sig[9] = {0.1f, 0.1f, 0.1f, 50.f, 50.f, 50.f, 10.f, 10.f, 10.f};
    const int pid = blockIdx.x * 256 + threadIdx.x;
    const int h   = pid >> 7;
    const int w   = pid & 127;

    float v[16] = {};
#pragma unroll
    for (int bh = 0; bh < 5; ++bh) {
        const int base = (bh * NPIX + pid) * 4;
#pragma unroll
        for (int k = 0; k < 4; ++k) {
            const float4 q = ws[base + k];
            v[k * 4 + 0] += q.x; v[k * 4 + 1] += q.y;
            v[k * 4 + 2] += q.z; v[k * 4 + 3] += q.w;
        }
    }

    // qc and allz from centers
    float qc[4] = {0.f, 0.f, 0.f, 0.f};
#pragma unroll
    for (int c = 0; c < 9; ++c) {
        float g[4];
        load4(guid + c * NPIX + pid, g);
#pragma unroll
        for (int t = 0; t < 4; ++t) qc[t] += sig[c] * g[t] * g[t];
    }
    float ecv[3][4];
#pragma unroll
    for (int c = 0; c < 3; ++c) load4(est + c * NPIX + pid, ecv[c]);

    // OOB (zero-padded) patches: member iff all ec==0; bw = exp(-qc/2)
    const int nh  = min(h + 2, H - 1) - max(h - 2, 0) + 1;
    const int nw  = min(w + 2, W - 1) - max(w - 2, 0) + 1;
    const int nhw = nh * nw;
    const int ntt[4] = {3, 4, 4, 3};
#pragma unroll
    for (int t = 0; t < 4; ++t) {
        const int oob = 125 - nhw * ntt[t];
        const bool allz = (ecv[0][t] == 0.f) && (ecv[1][t] == 0.f) && (ecv[2][t] == 0.f);
        const float f = allz ? __expf(-0.5f * qc[t]) : 0.f;
        v[12 + t] += (float)oob * f;
    }

#pragma unroll
    for (int t = 0; t < 4; ++t) {
        const float inv = 1.0f / fmaxf(v[12 + t], 1e-12f);
#pragma unroll
        for (int c = 0; c < 3; ++c) v[c * 4 + t] *= inv;
    }
#pragma unroll
    for (int c = 0; c < 3; ++c) {
        float4 o;
        o.x = v[c * 4 + 0]; o.y = v[c * 4 + 1];
        o.z = v[c * 4 + 2]; o.w = v[c * 4 + 3];
        out[c * NPIX + pid] = o;
    }
}

// ================= Fallback: round-2 single kernel (proven, 24.5 us) =================
__global__ __launch_bounds__(320, 2) void statden_fb(
    const float4* __restrict__ noisy, const float4* __restrict__ guid,
    const float4* __restrict__ est,   const float4* __restrict__ var,
    float4* __restrict__ out)
{
    const float sig[9] = {0.1f, 0.1f, 0.1f, 50.f, 50.f, 50.f, 10.f, 10.f, 10.f};
    const int tid = threadIdx.x;
    const int p   = tid & 63;
    const int s   = tid >> 6;
    const int pid = blockIdx.x * 64 + p;
    const int h   = pid >> 7;
    const int w   = pid & 127;

    float sgc[9][4], qc[4] = {0.f, 0.f, 0.f, 0.f};
    float ecv[3][4], vcv[3][4];
    {
        float g[4];
#pragma unroll
        for (int c = 0; c < 9; ++c) {
            load4(guid + c * NPIX + pid, g);
#pragma unroll
            for (int t = 0; t < 4; ++t) { sgc[c][t] = sig[c] * g[t]; qc[t] += sgc[c][t] * g[t]; }
        }
#pragma unroll
        for (int c = 0; c < 3; ++c) {
            load4(est + c * NPIX + pid, ecv[c]);
            load4(var + c * NPIX + pid, vcv[c]);
        }
    }

    float acc[3][4] = {};
    float den[4] = {0.f, 0.f, 0.f, 0.f};
    const int hh = h + s - 2;
    if ((unsigned)hh < (unsigned)H) {
#pragma unroll
        for (int dj = -2; dj <= 2; ++dj) {
            const int ww = w + dj;
            if ((unsigned)ww >= (unsigned)W) continue;
            const int q = hh * W + ww;
            float gj[9][4], ej[3][4], vj[3][4], nj[3][4];
#pragma unroll
            for (int c = 0; c < 9; ++c) load4(guid + c * NPIX + q, gj[c]);
#pragma unroll
            for (int c = 0; c < 3; ++c) {
                load4(est + c * NPIX + q, ej[c]);
                load4(var + c * NPIX + q, vj[c]);
                load4(noisy + c * NPIX + q, nj[c]);
            }
#pragma unroll
            for (int tt = 0; tt < 4; ++tt) {
                float qj = 0.f;
#pragma unroll
                for (int c = 0; c < 9; ++c) qj += sig[c] * gj[c][tt] * gj[c][tt];
                float cross[4] = {0.f, 0.f, 0.f, 0.f};
#pragma unroll
                for (int c = 0; c < 9; ++c) {
                    const float gv = gj[c][tt];
#pragma unroll
                    for (int t = 0; t < 4; ++t) cross[t] += gv * sgc[c][t];
                }
#pragma unroll
                for (int t = 0; t < 4; ++t) {
                    if (tt - t > 2 || t - tt > 2) continue;
                    const float sv = qj + qc[t] - 2.f * cross[t];
                    bool member = true;
#pragma unroll
                    for (int c = 0; c < 3; ++c) {
                        const float d = ecv[c][t] - ej[c][tt];
                        const float S = vcv[c][t] + vj[c][tt];
                        const float num = 2.f * d * d + S;
                        const float dn  = num + S;
                        bool pass = (num <= WMAX * dn);
                        if (((vcv[c][t] == 0.f) || (vj[c][tt] == 0.f)) && (d != 0.f)) pass = false;
                        member = member && pass;
                    }
                    const float f = member ? __expf(-0.5f * sv) : 0.f;
                    den[t] += f;
#pragma unroll
                    for (int c = 0; c < 3; ++c) acc[c][t] += f * nj[c][tt];
                }
            }
        }
    }

    __shared__ float red[5][64][17];
    {
        float* r = &red[s][p][0];
#pragma unroll
        for (int c = 0; c < 3; ++c)
#pragma unroll
            for (int t = 0; t < 4; ++t) r[c * 4 + t] = acc[c][t];
#pragma unroll
        for (int t = 0; t < 4; ++t) r[12 + t] = den[t];
    }
    __syncthreads();
    if (tid < 64) {
#pragma unroll
        for (int c = 0; c < 3; ++c)
#pragma unroll
            for (int t = 0; t < 4; ++t) acc[c][t] = red[0][p][c * 4 + t];
#pragma unroll
        for (int t = 0; t < 4; ++t) den[t] = red[0][p][12 + t];
#pragma unroll
        for (int k = 1; k < 5; ++k) {
            const float* r2 = &red[k][p][0];
#pragma unroll
            for (int c = 0; c < 3; ++c)
#pragma unroll
                for (int t = 0; t < 4; ++t) acc[c][t] += r2[c * 4 + t];
#pragma unroll
            for (int t = 0; t < 4; ++t) den[t] += r2[12 + t];
        }
        const int nh  = min(h + 2, H - 1) - max(h - 2, 0) + 1;
        const int nw  = min(w + 2, W - 1) - max(w - 2, 0) + 1;
        const int nhw = nh * nw;
        const int ntt[4] = {3, 4, 4, 3};
#pragma unroll
        for (int t = 0; t < 4; ++t) {
            const int oob = 125 - nhw * ntt[t];
            const bool allz = (ecv[0][t] == 0.f) && (ecv[1][t] == 0.f) && (ecv[2][t] == 0.f);
            const float f = allz ? __expf(-0.5f * qc[t]) : 0.f;
            den[t] += (float)oob * f;
        }
#pragma unroll
        for (int t = 0; t < 4; ++t) {
            const float inv = 1.0f / fmaxf(den[t], 1e-12f);
#pragma unroll
            for (int c = 0; c < 3; ++c) acc[c][t] *= inv;
        }
#pragma unroll
        for (int c = 0; c < 3; ++c) {
            float4 o;
            o.x = acc[c][0]; o.y = acc[c][1]; o.z = acc[c][2]; o.w = acc[c][3];
            out[c * NPIX + pid] = o;
        }
    }
}

} // namespace

extern "C" void kernel_launch(void* const* d_in, const int* in_sizes, int n_in,
                              void* d_out, int out_size, void* d_ws, size_t ws_size,
                              hipStream_t stream)
{
    const float4* noisy = (const float4*)d_in[0];
    const float4* guid  = (const float4*)d_in[1];
    const float4* est   = (const float4*)d_in[2];
    const float4* var   = (const float4*)d_in[3];
    float4* out = (float4*)d_out;

    const size_t need = (size_t)5 * NPIX * 16 * sizeof(float);   // 5.25 MB partials
    if (ws_size >= need) {
        float4* ws = (float4*)d_ws;
        statden_part<<<(NPIX / 64) * 5, 320, 0, stream>>>(noisy, guid, est, var, ws);
        statden_final<<<NPIX / 256, 256, 0, stream>>>(guid, est, ws, out);
    } else {
        statden_fb<<<NPIX / 64, 320, 0, stream>>>(noisy, guid, est, var, out);
    }
}

// Round 8
// 25.817 us; speedup vs baseline: 2.8951x; 1.3181x over previous
//
#include <hip/hip_runtime.h>

namespace {

constexpr int H = 128, W = 128;
constexpr int NPIX = H * W;           // 16384 pixels, each float4 over T=4
constexpr float GAMMA_W = 3.3257199f;
// membership: t(w)<=gamma  <=>  d^2 <= gamma^2 * (vi+vj)   (+ var-zero override)
__device__ constexpr float GAM2 = (float)((double)GAMMA_W * (double)GAMMA_W);

// tile geometry: 4x16 pixels per block, halo 8x20 sites
constexpr int TR = 4, TC = 16;
constexpr int HR = TR + 4, HC = TC + 4;   // 8 x 20
constexpr int NSITE = HR * HC;            // 160
constexpr int NK = 18;                    // 9 guid(sqrt-sig folded) + 3 est + 3 var + 3 noisy
constexpr int KP = 19;                    // padded site stride in float4 (304 B: bank-friendly)
constexpr int NTHR = 512;                 // 64 px * 8 column-slices

// slice s (wave-uniform, 8 waves) owns columns {s, s+8, s+16} (+24 for s==0)
// of the 25 (di,dj) offsets; col -> di=col/5-2, dj=col%5-2.

__global__ __launch_bounds__(NTHR)
__attribute__((amdgpu_waves_per_eu(1, 2)))   // relax VGPR budget; LDS limits to 1 block/CU anyway
void statden(const float4* __restrict__ noisy,
             const float4* __restrict__ guid,
             const float4* __restrict__ est,
             const float4* __restrict__ var,
             float4* __restrict__ out)
{
    __shared__ float4 halo[NSITE * KP];   // 48640 B; later reused as reduction scratch

    const int tid   = threadIdx.x;
    const int tiler = blockIdx.x >> 3;    // 0..31
    const int tilec = blockIdx.x & 7;     // 0..7
    const int r0 = tiler * TR - 2;
    const int c0 = tilec * TC - 2;

    // ---- stage halo: zero-filled OOB reproduces reference zero-padding exactly ----
    for (int u = tid; u < NSITE * NK; u += NTHR) {
        const int k    = u / NSITE;          // channel slot 0..17 (near-uniform per wave)
        const int site = u - k * NSITE;      // consecutive lanes -> consecutive sites: coalesced
        const int sr = site / HC;
        const int scp = site - sr * HC;
        const int gr = r0 + sr;
        const int gc = c0 + scp;
        float4 v = make_float4(0.f, 0.f, 0.f, 0.f);
        if (((unsigned)gr < (unsigned)H) && ((unsigned)gc < (unsigned)W)) {
            const int gpix = (gr << 7) + gc;
            const float4* src;
            float sca = 1.f;
            if (k < 9) {
                src = guid + k * NPIX + gpix;
                // sqrt(sigma_inv): {0.1,50,10} -> fold into staged guidance so
                // qj/cross/qc need no per-use sigma multiplies
                sca = (k < 3) ? 0.31622776601683794f
                    : (k < 6) ? 7.0710678118654755f
                              : 3.1622776601683795f;
            } else if (k < 12) src = est   + (k - 9)  * NPIX + gpix;
            else if (k < 15)   src = var   + (k - 12) * NPIX + gpix;
            else               src = noisy + (k - 15) * NPIX + gpix;
            const float4 t4 = *src;
            v.x = t4.x * sca; v.y = t4.y * sca; v.z = t4.z * sca; v.w = t4.w * sca;
        }
        halo[site * KP + k] = v;
    }
    __syncthreads();

    // ---- compute: thread = (pixel p, slice s) ----
    const int p  = tid & 63;
    const int s  = tid >> 6;              // wave-uniform
    const int pr = p >> 4;                // 0..3
    const int pc = p & 15;                // 0..15

    const float4* cs = &halo[((pr + 2) * HC + (pc + 2)) * KP];

    // centers (hoisted; sqrt-sig already folded into guidance)
    float gc4[9][4];
    float qc[4] = {0.f, 0.f, 0.f, 0.f};
#pragma unroll
    for (int c = 0; c < 9; ++c) {
        const float4 g = cs[c];
        gc4[c][0] = g.x; gc4[c][1] = g.y; gc4[c][2] = g.z; gc4[c][3] = g.w;
#pragma unroll
        for (int t = 0; t < 4; ++t) qc[t] += gc4[c][t] * gc4[c][t];
    }
    float ecv[3][4], vcv[3][4];
#pragma unroll
    for (int c = 0; c < 3; ++c) {
        const float4 e = cs[9 + c];
        ecv[c][0] = e.x; ecv[c][1] = e.y; ecv[c][2] = e.z; ecv[c][3] = e.w;
        const float4 vv = cs[12 + c];
        vcv[c][0] = vv.x; vcv[c][1] = vv.y; vcv[c][2] = vv.z; vcv[c][3] = vv.w;
    }

    float acc[3][4] = {};
    float den[4] = {0.f, 0.f, 0.f, 0.f};

#pragma unroll
    for (int cc = 0; cc < 4; ++cc) {
        const int col = s + (cc << 3);
        if (col < 25) {                    // wave-uniform guard
            const int di = col / 5 - 2;
            const int dj = (col - (col / 5) * 5) - 2;
            const float4* js = &halo[((pr + 2 + di) * HC + (pc + 2 + dj)) * KP];

            // guidance quadratic: sv[t][tt] = qj[tt] + qc[t] - 2*cross[t][tt]
            float qj[4] = {0.f, 0.f, 0.f, 0.f};
            float cross[4][4] = {};
#pragma unroll
            for (int c = 0; c < 9; ++c) {
                const float4 g = js[c];
                const float gj[4] = {g.x, g.y, g.z, g.w};
#pragma unroll
                for (int tt = 0; tt < 4; ++tt) qj[tt] += gj[tt] * gj[tt];
#pragma unroll
                for (int t = 0; t < 4; ++t)
#pragma unroll
                    for (int tt = 0; tt < 4; ++tt) cross[t][tt] += gj[tt] * gc4[c][t];
            }

            // membership; pairs |t-tt|>2 are not patches -> start masked off
            float mf[4][4];
#pragma unroll
            for (int t = 0; t < 4; ++t)
#pragma unroll
                for (int tt = 0; tt < 4; ++tt)
                    mf[t][tt] = (tt - t > 2 || t - tt > 2) ? 0.f : 1.f;
#pragma unroll
            for (int c = 0; c < 3; ++c) {
                const float4 e = js[9 + c];
                const float4 vv = js[12 + c];
                const float ej[4] = {e.x, e.y, e.z, e.w};
                const float vj[4] = {vv.x, vv.y, vv.z, vv.w};
#pragma unroll
                for (int t = 0; t < 4; ++t) {
                    const float vi = vcv[c][t];
                    const float ei = ecv[c][t];
#pragma unroll
                    for (int tt = 0; tt < 4; ++tt) {
                        const float d  = ei - ej[tt];
                        const float d2 = d * d;
                        const float S  = vi + vj[tt];
                        bool pass = (d2 <= GAM2 * S);   // d=0,S=0 (den==0,w=0.5) -> 0<=0 pass
                        if (((vi == 0.f) || (vj[tt] == 0.f)) && (d != 0.f)) pass = false;
                        if (!pass) mf[t][tt] = 0.f;
                    }
                }
            }

            float f[4][4];
#pragma unroll
            for (int t = 0; t < 4; ++t)
#pragma unroll
                for (int tt = 0; tt < 4; ++tt)
                    f[t][tt] = mf[t][tt] * __expf(-0.5f * (qj[tt] + qc[t] - 2.f * cross[t][tt]));
#pragma unroll
            for (int t = 0; t < 4; ++t)
                den[t] += (f[t][0] + f[t][1]) + (f[t][2] + f[t][3]);
#pragma unroll
            for (int c = 0; c < 3; ++c) {
                const float4 n4 = js[15 + c];
                const float nj[4] = {n4.x, n4.y, n4.z, n4.w};
#pragma unroll
                for (int t = 0; t < 4; ++t) {
                    float a = f[t][0] * nj[0];
                    a = fmaf(f[t][1], nj[1], a);
                    a = fmaf(f[t][2], nj[2], a);
                    a = fmaf(f[t][3], nj[3], a);
                    acc[c][t] += a;
                }
            }
        }
    }

    // ---- reduce 8 slices; reuse halo LDS as float scratch (stride 17, 2-way max) ----
    __syncthreads();                       // all halo reads complete
    float* red = reinterpret_cast<float*>(halo);
    {
        float* r = red + (s * 64 + p) * 17;
#pragma unroll
        for (int c = 0; c < 3; ++c)
#pragma unroll
            for (int t = 0; t < 4; ++t) r[c * 4 + t] = acc[c][t];
#pragma unroll
        for (int t = 0; t < 4; ++t) r[12 + t] = den[t];
    }
    __syncthreads();

    if (tid < 64) {                        // s==0: this thread's qc/ecv are its pixel's centers
        float v[16];
        const float* rp = red + p * 17;
#pragma unroll
        for (int i = 0; i < 16; ++i) v[i] = rp[i];
#pragma unroll
        for (int k = 1; k < 8; ++k) {
            const float* rk = red + (k * 64 + p) * 17;
#pragma unroll
            for (int i = 0; i < 16; ++i) v[i] += rk[i];
        }

        // t-axis zero-padded patches: per (di,dj) offset, #dk landing outside [0,3]
        // is {2,1,1,2} per t; x25 offsets. member iff all ec==0; bw=exp(-qc/2).
        const float cnt[4] = {50.f, 25.f, 25.f, 50.f};
#pragma unroll
        for (int t = 0; t < 4; ++t) {
            const bool allz = (ecv[0][t] == 0.f) && (ecv[1][t] == 0.f) && (ecv[2][t] == 0.f);
            const float f0 = allz ? __expf(-0.5f * qc[t]) : 0.f;
            v[12 + t] += cnt[t] * f0;
        }

#pragma unroll
        for (int t = 0; t < 4; ++t) {
            const float inv = 1.f / fmaxf(v[12 + t], 1e-12f);
            v[0 + t] *= inv; v[4 + t] *= inv; v[8 + t] *= inv;
        }
        const int pid = ((tiler * TR + pr) << 7) + tilec * TC + pc;
#pragma unroll
        for (int c = 0; c < 3; ++c) {
            float4 o;
            o.x = v[c * 4 + 0]; o.y = v[c * 4 + 1];
            o.z = v[c * 4 + 2]; o.w = v[c * 4 + 3];
            out[c * NPIX + pid] = o;
        }
    }
}

} // namespace

extern "C" void kernel_launch(void* const* d_in, const int* in_sizes, int n_in,
                              void* d_out, int out_size, void* d_ws, size_t ws_size,
                              hipStream_t stream)
{
    const float4* noisy = (const float4*)d_in[0];
    const float4* guid  = (const float4*)d_in[1];
    const float4* est   = (const float4*)d_in[2];
    const float4* var   = (const float4*)d_in[3];
    float4* out = (float4*)d_out;

    statden<<<(H / TR) * (W / TC), NTHR, 0, stream>>>(noisy, guid, est, var, out);
}

// Round 9
// 15.011 us; speedup vs baseline: 4.9794x; 1.7199x over previous
//
#include <hip/hip_runtime.h>

typedef float v2f __attribute__((ext_vector_type(2)));

namespace {

constexpr int H = 128, W = 128, NPIX = H * W;
constexpr double GAMMA_Wd = 3.3257199;
constexpr float GAM2 = (float)(GAMMA_Wd * GAMMA_Wd);   // 11.0604...
constexpr float VBIG  = 1e30f;    // var' sentinel for var==0 (incl. OOB pad)
constexpr float NHUGE = -1e38f;   // d!=0 punishment; d>=2^-24 => |z|>=3.5e23

// tile geometry: 4x16 pixels per block, halo 8x20 sites
constexpr int TR = 4, TC = 16;
constexpr int HR = TR + 4, HC = TC + 4;   // 8 x 20
constexpr int NSITE = HR * HC;            // 160
constexpr int NK = 18;   // 9 guid*sqrt(sig/2) | 3 est | 3 var' | 3 noisy
constexpr int KP = 19;   // padded site stride in float4
constexpr int NTHR = 512;

__global__ __launch_bounds__(NTHR)
__attribute__((amdgpu_waves_per_eu(2, 8)))   // min=2 -> VGPR cap 256 (anti-spill, rounds 3/5/6)
void statden(const float4* __restrict__ noisy,
             const float4* __restrict__ guid,
             const float4* __restrict__ est,
             const float4* __restrict__ var,
             float4* __restrict__ out)
{
    __shared__ float4 halo[NSITE * KP];   // 48640 B; reused as reduce scratch

    const int tid   = threadIdx.x;
    const int tiler = blockIdx.x >> 3;
    const int tilec = blockIdx.x & 7;
    const int r0 = tiler * TR - 2;
    const int c0 = tilec * TC - 2;

    // ---- stage halo (transforms folded in) ----
    for (int u = tid; u < NSITE * NK; u += NTHR) {
        const int k    = u / NSITE;
        const int site = u - k * NSITE;
        const int sr  = site / HC;
        const int scp = site - sr * HC;
        const int gr = r0 + sr;
        const int gc = c0 + scp;
        const bool varslot = (k >= 12) && (k < 15);
        float4 v;
        if (((unsigned)gr < (unsigned)H) && ((unsigned)gc < (unsigned)W)) {
            const int gpix = (gr << 7) + gc;
            if (k < 9) {
                // sqrt(sigma/2): exp arg becomes 2*cross - qc~ - qj~ directly
                const float sca = (k < 3) ? 0.22360679774997896f
                                : (k < 6) ? 5.0f
                                          : 2.2360679774997896f;
                const float4 g = guid[k * NPIX + gpix];
                v = make_float4(g.x * sca, g.y * sca, g.z * sca, g.w * sca);
            } else if (k < 12) {
                v = est[(k - 9) * NPIX + gpix];
            } else if (k < 15) {
                // var' = (var==0) ? -VBIG : gamma^2 * var
                const float4 w4 = var[(k - 12) * NPIX + gpix];
                v.x = (w4.x == 0.f) ? -VBIG : GAM2 * w4.x;
                v.y = (w4.y == 0.f) ? -VBIG : GAM2 * w4.y;
                v.z = (w4.z == 0.f) ? -VBIG : GAM2 * w4.z;
                v.w = (w4.w == 0.f) ? -VBIG : GAM2 * w4.w;
            } else {
                v = noisy[(k - 15) * NPIX + gpix];
            }
        } else {
            // zero padding; var' pad = -VBIG makes OOB membership (= all ec==0)
            // fall out of the standard inner-loop path.
            const float pad = varslot ? -VBIG : 0.f;
            v = make_float4(pad, pad, pad, pad);
        }
        halo[site * KP + k] = v;
    }
    __syncthreads();

    // ---- compute: thread = (pixel p, slice s); slice owns cols {s,s+8,s+16,(s+24)} ----
    const int p  = tid & 63;
    const int s  = tid >> 6;          // wave-uniform
    const int pr = p >> 4;
    const int pc = p & 15;

    const float4* cs = &halo[((pr + 2) * HC + (pc + 2)) * KP];

    v2f gcc[9][2];                    // scaled center guidance, packed over t
    v2f nqc[2] = {{0.f, 0.f}, {0.f, 0.f}};   // -qc~
#pragma unroll
    for (int c = 0; c < 9; ++c) {
        const float4 g = cs[c];
        gcc[c][0] = (v2f){g.x, g.y};
        gcc[c][1] = (v2f){g.z, g.w};
        nqc[0] -= gcc[c][0] * gcc[c][0];
        nqc[1] -= gcc[c][1] * gcc[c][1];
    }
    v2f eiP[3][2], viP[3][2];
#pragma unroll
    for (int c = 0; c < 3; ++c) {
        const float4 e = cs[9 + c];
        eiP[c][0] = (v2f){e.x, e.y}; eiP[c][1] = (v2f){e.z, e.w};
        const float4 w4 = cs[12 + c];
        viP[c][0] = (v2f){w4.x, w4.y}; viP[c][1] = (v2f){w4.z, w4.w};
    }

    v2f accP[3][2] = {};
    v2f denP[2] = {};

#pragma unroll
    for (int cc = 0; cc < 4; ++cc) {
        const int col = s + (cc << 3);
        if (col < 25) {               // wave-uniform
            const int di = col / 5 - 2;
            const int dj = col - (col / 5) * 5 - 2;
            const float4* js = &halo[((pr + 2 + di) * HC + (pc + 2 + dj)) * KP];

            // guidance quadratic (packed)
            v2f qj2[2] = {};          // qj~ packed over tt
            v2f cr[4][2] = {};        // cross[tt][t-half]
#pragma unroll
            for (int c = 0; c < 9; ++c) {
                const float4 g = js[c];
                const v2f g01 = (v2f){g.x, g.y}, g23 = (v2f){g.z, g.w};
                qj2[0] += g01 * g01;  qj2[1] += g23 * g23;
                cr[0][0] += gcc[c][0] * g.x;  cr[0][1] += gcc[c][1] * g.x;
                cr[1][0] += gcc[c][0] * g.y;  cr[1][1] += gcc[c][1] * g.y;
                cr[2][0] += gcc[c][0] * g.z;  cr[2][1] += gcc[c][1] * g.z;
                cr[3][0] += gcc[c][0] * g.w;  cr[3][1] += gcc[c][1] * g.w;
            }

            // membership, pure arithmetic: rf = max(S' - d^2, -HUGE*d^2); pass <=> min_c rf >= 0
            v2f rm[4][2];
#pragma unroll
            for (int c = 0; c < 3; ++c) {
                const float4 e4 = js[9 + c];
                const float4 w4 = js[12 + c];
                const float ejs[4] = {e4.x, e4.y, e4.z, e4.w};
                const float vjs[4] = {w4.x, w4.y, w4.z, w4.w};
#pragma unroll
                for (int tt = 0; tt < 4; ++tt) {
#pragma unroll
                    for (int hf = 0; hf < 2; ++hf) {
                        const v2f d  = eiP[c][hf] - ejs[tt];
                        const v2f S  = viP[c][hf] + vjs[tt];
                        const v2f dd = d * d;
                        const v2f r  = S - dd;
                        const v2f z  = dd * NHUGE;
                        const v2f rf = __builtin_elementwise_max(r, z);
                        rm[tt][hf] = (c == 0) ? rf
                                   : __builtin_elementwise_min(rm[tt][hf], rf);
                    }
                }
            }

            // weights + accumulate
            v2f f01[4], f23[4];
#pragma unroll
            for (int tt = 0; tt < 4; ++tt) {
                const float qjt = qj2[tt >> 1][tt & 1];
                const v2f a0 = cr[tt][0] * 2.f + (nqc[0] - qjt);
                const v2f a1 = cr[tt][1] * 2.f + (nqc[1] - qjt);
                float fv[4];
#pragma unroll
                for (int t = 0; t < 4; ++t) {
                    const bool valid = (tt - t <= 2) && (t - tt <= 2);
                    if (valid) {
                        const float av = (t < 2) ? a0[t & 1] : a1[t & 1];
                        const float rv = (t < 2) ? rm[tt][0][t & 1] : rm[tt][1][t & 1];
                        const float e  = __expf(av);
                        fv[t] = (rv >= 0.f) ? e : 0.f;
                    } else {
                        fv[t] = 0.f;
                    }
                }
                f01[tt] = (v2f){fv[0], fv[1]};
                f23[tt] = (v2f){fv[2], fv[3]};
                denP[0] += f01[tt];
                denP[1] += f23[tt];
            }
#pragma unroll
            for (int c = 0; c < 3; ++c) {
                const float4 n4 = js[15 + c];
                const float njs[4] = {n4.x, n4.y, n4.z, n4.w};
#pragma unroll
                for (int tt = 0; tt < 4; ++tt) {
                    accP[c][0] += f01[tt] * njs[tt];
                    accP[c][1] += f23[tt] * njs[tt];
                }
            }
        }
    }

    // ---- reduce 8 slices; reuse halo LDS as float scratch (stride 17) ----
    __syncthreads();
    float* red = reinterpret_cast<float*>(halo);
    {
        float* r = red + (s * 64 + p) * 17;
#pragma unroll
        for (int c = 0; c < 3; ++c) {
            r[c * 4 + 0] = accP[c][0][0]; r[c * 4 + 1] = accP[c][0][1];
            r[c * 4 + 2] = accP[c][1][0]; r[c * 4 + 3] = accP[c][1][1];
        }
        r[12] = denP[0][0]; r[13] = denP[0][1];
        r[14] = denP[1][0]; r[15] = denP[1][1];
    }
    __syncthreads();

    if (tid < 64) {                   // s==0: this thread's centers are its pixel's
        float v[16];
        const float* rp = red + p * 17;
#pragma unroll
        for (int i = 0; i < 16; ++i) v[i] = rp[i];
#pragma unroll
        for (int k = 1; k < 8; ++k) {
            const float* rk = red + (k * 64 + p) * 17;
#pragma unroll
            for (int i = 0; i < 16; ++i) v[i] += rk[i];
        }

        // t-axis zero-padded patches: {2,1,1,2} dk-OOB per t, x25 offsets.
        // member iff all ec==0; bw = exp(-qc~) since qc~ = 0.5*sum(sig*gc^2).
        const float cnt[4] = {50.f, 25.f, 25.f, 50.f};
        const float qn[4]  = {nqc[0][0], nqc[0][1], nqc[1][0], nqc[1][1]};
        const float e0[4]  = {eiP[0][0][0], eiP[0][0][1], eiP[0][1][0], eiP[0][1][1]};
        const float e1[4]  = {eiP[1][0][0], eiP[1][0][1], eiP[1][1][0], eiP[1][1][1]};
        const float e2[4]  = {eiP[2][0][0], eiP[2][0][1], eiP[2][1][0], eiP[2][1][1]};
#pragma unroll
        for (int t = 0; t < 4; ++t) {
            const bool allz = (e0[t] == 0.f) && (e1[t] == 0.f) && (e2[t] == 0.f);
            const float f0 = allz ? __expf(qn[t]) : 0.f;
            v[12 + t] += cnt[t] * f0;
        }

#pragma unroll
        for (int t = 0; t < 4; ++t) {
            const float inv = 1.f / fmaxf(v[12 + t], 1e-12f);
            v[0 + t] *= inv; v[4 + t] *= inv; v[8 + t] *= inv;
        }
        const int pid = ((tiler * TR + pr) << 7) + tilec * TC + pc;
#pragma unroll
        for (int c = 0; c < 3; ++c) {
            float4 o;
            o.x = v[c * 4 + 0]; o.y = v[c * 4 + 1];
            o.z = v[c * 4 + 2]; o.w = v[c * 4 + 3];
            out[c * NPIX + pid] = o;
        }
    }
}

} // namespace

extern "C" void kernel_launch(void* const* d_in, const int* in_sizes, int n_in,
                              void* d_out, int out_size, void* d_ws, size_t ws_size,
                              hipStream_t stream)
{
    const float4* noisy = (const float4*)d_in[0];
    const float4* guid  = (const float4*)d_in[1];
    const float4* est   = (const float4*)d_in[2];
    const float4* var   = (const float4*)d_in[3];
    float4* out = (float4*)d_out;

    statden<<<(H / TR) * (W / TC), NTHR, 0, stream>>>(noisy, guid, est, var, out);
}